// Round 4
// baseline (52.057 us; speedup 1.0000x reference)
//
#include <hip/hip_runtime.h>
#include <math.h>

// Ordinal regression loss: mean over (B, K=4) of
//   max(x,0) - x*[k < label] + log1p(exp(-|x|))
// Single-kernel streaming reduction. Final reduce fused via ONE u64
// atomicAdd per block encoding {ticket (bits 52+), fixed-point partial
// sum (low 52 bits, 2^-21 units)}. Integer adds commute -> deterministic.
// No __threadfence (round-2 lesson: device-scope fences x2048 are toxic).

#define KDIM 4
#define BLOCK 256
#define GRID 2048
#define FIXSCALE 2097152.0  // 2^21

__device__ __forceinline__ float row_loss(float4 x, int lab) {
    float xs[KDIM] = {x.x, x.y, x.z, x.w};
    float acc = 0.0f;
#pragma unroll
    for (int k = 0; k < KDIM; ++k) {
        float v = xs[k];
        float t = (k < lab) ? 1.0f : 0.0f;
        float a = fabsf(v);
        // softplus(-a) = log(1 + exp(-a)), a >= 0 so exp(-a) <= 1 (stable)
        float sp = __logf(1.0f + __expf(-a));
        acc += fmaxf(v, 0.0f) - v * t + sp;
    }
    return acc;
}

__global__ __launch_bounds__(BLOCK) void ordloss_fused(
    const float4* __restrict__ logits,   // B rows, one float4 per row (K=4)
    const int* __restrict__ labels,      // B int32
    unsigned long long* __restrict__ acc_word,  // 1 u64 in d_ws, zeroed per call
    float* __restrict__ out,             // 1 float
    int B, float inv_count)
{
    int tid = blockIdx.x * BLOCK + threadIdx.x;
    const int stride = GRID * BLOCK;

    // Round-1 proven memory loop: one coalesced float4 + one int per iter,
    // compiler pipelines the next iteration's loads under this one's compute.
    float acc = 0.0f;
    for (int i = tid; i < B; i += stride)
        acc += row_loss(logits[i], labels[i]);

    // wave64 shuffle reduction
#pragma unroll
    for (int off = 32; off > 0; off >>= 1)
        acc += __shfl_down(acc, off, 64);

    __shared__ float wsum[BLOCK / 64];
    int lane = threadIdx.x & 63;
    int wid  = threadIdx.x >> 6;
    if (lane == 0) wsum[wid] = acc;
    __syncthreads();
    if (threadIdx.x == 0) {
        float s = wsum[0] + wsum[1] + wsum[2] + wsum[3];
        // encode: ticket in bits [52..], fixed-point sum in low 52 bits.
        // s >= 0 (loss is non-negative); block sum < 1.2e5 -> s*2^21 < 2^38;
        // total across 2048 blocks < 2^49 < 2^52. No overflow into ticket.
        unsigned long long enc =
            (1ULL << 52) + (unsigned long long)((double)s * FIXSCALE + 0.5);
        unsigned long long old = atomicAdd(acc_word, enc);
        if ((old >> 52) == (unsigned long long)(GRID - 1)) {
            // I'm the last block: old + enc is the exact final word.
            unsigned long long total = (old + enc) & ((1ULL << 52) - 1);
            out[0] = (float)((double)total / FIXSCALE * (double)inv_count);
        }
    }
}

extern "C" void kernel_launch(void* const* d_in, const int* in_sizes, int n_in,
                              void* d_out, int out_size, void* d_ws, size_t ws_size,
                              hipStream_t stream) {
    const float4* logits = (const float4*)d_in[0];
    const int*    labels = (const int*)d_in[1];
    float*        out    = (float*)d_out;
    unsigned long long* acc_word = (unsigned long long*)d_ws;

    int B = in_sizes[1];  // labels count = rows
    float inv_count = 1.0f / ((float)B * (float)KDIM);

    hipMemsetAsync(acc_word, 0, sizeof(unsigned long long), stream);
    ordloss_fused<<<GRID, BLOCK, 0, stream>>>(logits, labels, acc_word,
                                              out, B, inv_count);
}

// Round 5
// 37.543 us; speedup vs baseline: 1.3866x; 1.3866x over previous
//
#include <hip/hip_runtime.h>
#include <math.h>

// Ordinal regression loss: mean over (B, K=4) of
//   max(x,0) - x*[k < label] + log1p(exp(-|x|))
// Streaming reduction, fused final reduce via two-level fixed-point
// atomic tickets (no fences, no memset node — round-2/round-4 lessons:
// __threadfence x2048 is toxic, and hipMemsetAsync's fill kernel has
// ~75us fixed cost in the graph). Reset done by a 1-wave micro-kernel.

#define KDIM 4
#define BLOCK 256
#define GRID 2048
#define NGROUP 32                 // 2048 blocks -> 32 leaves of 64
#define FIXSCALE 2097152.0        // 2^21
#define LOW52 ((1ULL << 52) - 1)

// ws layout (u64 stride 16 = 128B apart, distinct cache lines):
//   ws[0]          : root word   {ticket[52..], fixed-point sum[0..51]}
//   ws[(g+1)*16]   : leaf word g (g = 0..31)

__global__ __launch_bounds__(64) void ordloss_reset(unsigned long long* __restrict__ ws) {
    int t = threadIdx.x;
    if (t <= NGROUP) ws[t * 16] = 0ULL;
}

__device__ __forceinline__ float row_loss(float4 x, int lab) {
    float xs[KDIM] = {x.x, x.y, x.z, x.w};
    float acc = 0.0f;
#pragma unroll
    for (int k = 0; k < KDIM; ++k) {
        float v = xs[k];
        float t = (k < lab) ? 1.0f : 0.0f;
        float a = fabsf(v);
        // softplus(-a) = log(1 + exp(-a)), a >= 0 so exp(-a) <= 1 (stable)
        float sp = __logf(1.0f + __expf(-a));
        acc += fmaxf(v, 0.0f) - v * t + sp;
    }
    return acc;
}

__global__ __launch_bounds__(BLOCK) void ordloss_fused(
    const float4* __restrict__ logits,   // B rows, one float4 per row (K=4)
    const int* __restrict__ labels,      // B int32
    unsigned long long* __restrict__ ws, // root + leaf ticket words
    float* __restrict__ out,             // 1 float
    int B, float inv_count)
{
    int tid = blockIdx.x * BLOCK + threadIdx.x;
    const int stride = GRID * BLOCK;

    // Round-1 proven memory loop: one coalesced float4 + one int per iter.
    float acc = 0.0f;
    for (int i = tid; i < B; i += stride)
        acc += row_loss(logits[i], labels[i]);

    // wave64 shuffle reduction
#pragma unroll
    for (int off = 32; off > 0; off >>= 1)
        acc += __shfl_down(acc, off, 64);

    __shared__ float wsum[BLOCK / 64];
    int lane = threadIdx.x & 63;
    int wid  = threadIdx.x >> 6;
    if (lane == 0) wsum[wid] = acc;
    __syncthreads();
    if (threadIdx.x == 0) {
        float s = wsum[0] + wsum[1] + wsum[2] + wsum[3];
        // Fixed-point encode; integer atomics commute -> bit-deterministic.
        // Block sum < 1.2e5 -> fix < 2^38; leaf < 64*2^38 = 2^44;
        // root < 32*2^44 = 2^49 < 2^52 ticket bit. No overflow.
        unsigned long long enc =
            (1ULL << 52) + (unsigned long long)((double)s * FIXSCALE + 0.5);
        int g = blockIdx.x >> 6;                 // 64 blocks per leaf
        unsigned long long old = atomicAdd(&ws[(g + 1) * 16], enc);
        if ((old >> 52) == 63) {                 // last block of this leaf
            unsigned long long leafsum = (old + enc) & LOW52;
            unsigned long long enc2 = (1ULL << 52) + leafsum;
            unsigned long long old2 = atomicAdd(&ws[0], enc2);
            if ((old2 >> 52) == NGROUP - 1) {    // last leaf overall
                unsigned long long total = (old2 + enc2) & LOW52;
                out[0] = (float)((double)total / FIXSCALE * (double)inv_count);
            }
        }
    }
}

extern "C" void kernel_launch(void* const* d_in, const int* in_sizes, int n_in,
                              void* d_out, int out_size, void* d_ws, size_t ws_size,
                              hipStream_t stream) {
    const float4* logits = (const float4*)d_in[0];
    const int*    labels = (const int*)d_in[1];
    float*        out    = (float*)d_out;
    unsigned long long* ws = (unsigned long long*)d_ws;

    int B = in_sizes[1];  // labels count = rows
    float inv_count = 1.0f / ((float)B * (float)KDIM);

    ordloss_reset<<<1, 64, 0, stream>>>(ws);
    ordloss_fused<<<GRID, BLOCK, 0, stream>>>(logits, labels, ws,
                                              out, B, inv_count);
}

// Round 6
// 34.011 us; speedup vs baseline: 1.5306x; 1.1038x over previous
//
#include <hip/hip_runtime.h>
#include <math.h>

// Ordinal regression loss: mean over (B, K=4) of
//   max(x,0) - x*[k < label] + log1p(exp(-|x|))  ==  softplus(s*x), s=+-1
// Round-1 proven two-kernel structure (every fusion attempt regressed:
// r2 fences 100us, r4 memset-node 52us, r5 atomic-ticket 37.5us).
// Round 6 levers: nontemporal streaming loads + softplus identity +
// float4 final reduce.

#define KDIM 4
#define BLOCK 256
#define GRID 2048

typedef float f32x4 __attribute__((ext_vector_type(4)));

__device__ __forceinline__ float row_loss(f32x4 x, int lab) {
    float acc = 0.0f;
#pragma unroll
    for (int k = 0; k < KDIM; ++k) {
        float v = x[k];
        // BCE-with-logits == softplus(z), z = (target ? -v : v)
        float z = (k < lab) ? -v : v;
        float a = fabsf(v);
        // softplus(z) = max(z,0) + log1p(exp(-|z|)), |z| == |v|
        acc += fmaxf(z, 0.0f) + __logf(1.0f + __expf(-a));
    }
    return acc;
}

__global__ __launch_bounds__(BLOCK) void ordloss_partial(
    const f32x4* __restrict__ logits,    // B rows, one float4 per row (K=4)
    const int* __restrict__ labels,      // B int32
    float* __restrict__ partial,         // GRID floats
    int B)
{
    int tid = blockIdx.x * BLOCK + threadIdx.x;
    const int stride = GRID * BLOCK;

    float acc = 0.0f;
    for (int i = tid; i < B; i += stride) {
        f32x4 x = __builtin_nontemporal_load(logits + i);
        int lab  = __builtin_nontemporal_load(labels + i);
        acc += row_loss(x, lab);
    }

    // wave64 shuffle reduction
#pragma unroll
    for (int off = 32; off > 0; off >>= 1)
        acc += __shfl_down(acc, off, 64);

    __shared__ float wsum[BLOCK / 64];
    int lane = threadIdx.x & 63;
    int wid  = threadIdx.x >> 6;
    if (lane == 0) wsum[wid] = acc;
    __syncthreads();
    if (threadIdx.x == 0) {
        float s = wsum[0] + wsum[1] + wsum[2] + wsum[3];
        partial[blockIdx.x] = s;
    }
}

__global__ __launch_bounds__(BLOCK) void ordloss_final(
    const f32x4* __restrict__ partial4,  // GRID/4 float4s
    float* __restrict__ out, float inv_count)
{
    // GRID=2048 partials = 512 float4; 256 threads x 2 float4 each.
    f32x4 a = partial4[threadIdx.x];
    f32x4 b = partial4[threadIdx.x + BLOCK];
    float acc = (a[0] + a[1]) + (a[2] + a[3]) + (b[0] + b[1]) + (b[2] + b[3]);

#pragma unroll
    for (int off = 32; off > 0; off >>= 1)
        acc += __shfl_down(acc, off, 64);

    __shared__ float wsum[BLOCK / 64];
    int lane = threadIdx.x & 63;
    int wid  = threadIdx.x >> 6;
    if (lane == 0) wsum[wid] = acc;
    __syncthreads();
    if (threadIdx.x == 0) {
        float s = wsum[0] + wsum[1] + wsum[2] + wsum[3];
        out[0] = s * inv_count;
    }
}

extern "C" void kernel_launch(void* const* d_in, const int* in_sizes, int n_in,
                              void* d_out, int out_size, void* d_ws, size_t ws_size,
                              hipStream_t stream) {
    const f32x4* logits = (const f32x4*)d_in[0];
    const int*   labels = (const int*)d_in[1];
    float*       out    = (float*)d_out;
    float*       partial = (float*)d_ws;   // GRID floats = 8 KiB

    int B = in_sizes[1];  // labels count = rows
    float inv_count = 1.0f / ((float)B * (float)KDIM);

    ordloss_partial<<<GRID, BLOCK, 0, stream>>>(logits, labels, partial, B);
    ordloss_final<<<1, BLOCK, 0, stream>>>((const f32x4*)partial, out, inv_count);
}

// Round 7
// 33.411 us; speedup vs baseline: 1.5581x; 1.0180x over previous
//
#include <hip/hip_runtime.h>
#include <math.h>

// Ordinal regression loss: mean over (B, K=4) of
//   max(x,0) - x*[k < label] + log1p(exp(-|x|))  ==  softplus(s*x), s=+-1
// Two-kernel streaming reduction (all fusion variants regressed:
// r2 fences 100us, r4 memset-node 52us, r5 atomic-ticket 37.5us).
// Round 7: block-local 2-row unroll — 40B in flight per thread while the
// block footprint stays contiguous (round-3 lesson: grid-stride unroll
// with 8MB-distant loads kills locality).

#define KDIM 4
#define BLOCK 256
#define GRID 2048

typedef float f32x4 __attribute__((ext_vector_type(4)));

__device__ __forceinline__ float row_loss(f32x4 x, int lab) {
    float acc = 0.0f;
#pragma unroll
    for (int k = 0; k < KDIM; ++k) {
        float v = x[k];
        // BCE-with-logits == softplus(z), z = (target ? -v : v)
        float z = (k < lab) ? -v : v;
        float a = fabsf(v);
        // softplus(z) = max(z,0) + log1p(exp(-|z|)), |z| == |v|
        acc += fmaxf(z, 0.0f) + __logf(1.0f + __expf(-a));
    }
    return acc;
}

__global__ __launch_bounds__(BLOCK) void ordloss_partial(
    const f32x4* __restrict__ logits,    // B rows, one float4 per row (K=4)
    const int* __restrict__ labels,      // B int32
    float* __restrict__ partial,         // GRID floats
    int B)
{
    const int t = threadIdx.x;
    const int TILE = 2 * BLOCK;               // rows per block per outer iter
    const long ostride = (long)GRID * TILE;

    float acc = 0.0f;
    for (long base = (long)blockIdx.x * TILE; base < B; base += ostride) {
        long i0 = base + t;
        long i1 = base + BLOCK + t;
        if (i1 < B) {
            // two coalesced row-loads 1 KiB apart: 40B/lane in flight
            f32x4 x0 = __builtin_nontemporal_load(logits + i0);
            f32x4 x1 = __builtin_nontemporal_load(logits + i1);
            int l0 = __builtin_nontemporal_load(labels + i0);
            int l1 = __builtin_nontemporal_load(labels + i1);
            acc += row_loss(x0, l0);
            acc += row_loss(x1, l1);
        } else if (i0 < B) {
            f32x4 x0 = __builtin_nontemporal_load(logits + i0);
            int l0 = __builtin_nontemporal_load(labels + i0);
            acc += row_loss(x0, l0);
        }
    }

    // wave64 shuffle reduction
#pragma unroll
    for (int off = 32; off > 0; off >>= 1)
        acc += __shfl_down(acc, off, 64);

    __shared__ float wsum[BLOCK / 64];
    int lane = threadIdx.x & 63;
    int wid  = threadIdx.x >> 6;
    if (lane == 0) wsum[wid] = acc;
    __syncthreads();
    if (threadIdx.x == 0) {
        float s = wsum[0] + wsum[1] + wsum[2] + wsum[3];
        partial[blockIdx.x] = s;
    }
}

__global__ __launch_bounds__(BLOCK) void ordloss_final(
    const f32x4* __restrict__ partial4,  // GRID/4 float4s
    float* __restrict__ out, float inv_count)
{
    // GRID=2048 partials = 512 float4; 256 threads x 2 float4 each.
    f32x4 a = partial4[threadIdx.x];
    f32x4 b = partial4[threadIdx.x + BLOCK];
    float acc = (a[0] + a[1]) + (a[2] + a[3]) + (b[0] + b[1]) + (b[2] + b[3]);

#pragma unroll
    for (int off = 32; off > 0; off >>= 1)
        acc += __shfl_down(acc, off, 64);

    __shared__ float wsum[BLOCK / 64];
    int lane = threadIdx.x & 63;
    int wid  = threadIdx.x >> 6;
    if (lane == 0) wsum[wid] = acc;
    __syncthreads();
    if (threadIdx.x == 0) {
        float s = wsum[0] + wsum[1] + wsum[2] + wsum[3];
        out[0] = s * inv_count;
    }
}

extern "C" void kernel_launch(void* const* d_in, const int* in_sizes, int n_in,
                              void* d_out, int out_size, void* d_ws, size_t ws_size,
                              hipStream_t stream) {
    const f32x4* logits = (const f32x4*)d_in[0];
    const int*   labels = (const int*)d_in[1];
    float*       out    = (float*)d_out;
    float*       partial = (float*)d_ws;   // GRID floats = 8 KiB

    int B = in_sizes[1];  // labels count = rows
    float inv_count = 1.0f / ((float)B * (float)KDIM);

    ordloss_partial<<<GRID, BLOCK, 0, stream>>>(logits, labels, partial, B);
    ordloss_final<<<1, BLOCK, 0, stream>>>((const f32x4*)partial, out, inv_count);
}

// Round 8
// 31.478 us; speedup vs baseline: 1.6538x; 1.0614x over previous
//
#include <hip/hip_runtime.h>
#include <math.h>

// Ordinal regression loss: mean over (B, K=4) of
//   max(x,0) - x*[k < label] + log1p(exp(-|x|))  ==  softplus(s*x), s=+-1
// Two-kernel streaming reduction (all fusion variants regressed:
// r2 fences 100us, r4 memset-node 52us, r5 atomic-ticket 37.5us).
// Round 8: block-local 4-row unroll (TILE=1024), 80B/lane in flight,
// every load instruction lane-contiguous, tile-granular bounds check.

#define KDIM 4
#define BLOCK 256
#define GRID 2048
#define ROWS 4                      // rows per thread per outer iter
#define TILE (ROWS * BLOCK)         // 1024 rows per block per outer iter

typedef float f32x4 __attribute__((ext_vector_type(4)));

__device__ __forceinline__ float row_loss(f32x4 x, int lab) {
    float acc = 0.0f;
#pragma unroll
    for (int k = 0; k < KDIM; ++k) {
        float v = x[k];
        // BCE-with-logits == softplus(z), z = (target ? -v : v)
        float z = (k < lab) ? -v : v;
        float a = fabsf(v);
        // softplus(z) = max(z,0) + log1p(exp(-|z|)), |z| == |v|
        acc += fmaxf(z, 0.0f) + __logf(1.0f + __expf(-a));
    }
    return acc;
}

__global__ __launch_bounds__(BLOCK) void ordloss_partial(
    const f32x4* __restrict__ logits,    // B rows, one float4 per row (K=4)
    const int* __restrict__ labels,      // B int32
    float* __restrict__ partial,         // GRID floats
    int B)
{
    const int t = threadIdx.x;
    const long ostride = (long)GRID * TILE;

    float acc = 0.0f;
    for (long base = (long)blockIdx.x * TILE; base < B; base += ostride) {
        if (base + TILE <= B) {
            // fast path: branch-free, 4 coalesced f32x4 + 4 coalesced int
            f32x4 x0 = __builtin_nontemporal_load(logits + base + 0 * BLOCK + t);
            f32x4 x1 = __builtin_nontemporal_load(logits + base + 1 * BLOCK + t);
            f32x4 x2 = __builtin_nontemporal_load(logits + base + 2 * BLOCK + t);
            f32x4 x3 = __builtin_nontemporal_load(logits + base + 3 * BLOCK + t);
            int l0 = __builtin_nontemporal_load(labels + base + 0 * BLOCK + t);
            int l1 = __builtin_nontemporal_load(labels + base + 1 * BLOCK + t);
            int l2 = __builtin_nontemporal_load(labels + base + 2 * BLOCK + t);
            int l3 = __builtin_nontemporal_load(labels + base + 3 * BLOCK + t);
            acc += row_loss(x0, l0);
            acc += row_loss(x1, l1);
            acc += row_loss(x2, l2);
            acc += row_loss(x3, l3);
        } else {
#pragma unroll
            for (int r = 0; r < ROWS; ++r) {
                long i = base + r * BLOCK + t;
                if (i < B) {
                    f32x4 x = __builtin_nontemporal_load(logits + i);
                    int l = __builtin_nontemporal_load(labels + i);
                    acc += row_loss(x, l);
                }
            }
        }
    }

    // wave64 shuffle reduction
#pragma unroll
    for (int off = 32; off > 0; off >>= 1)
        acc += __shfl_down(acc, off, 64);

    __shared__ float wsum[BLOCK / 64];
    int lane = threadIdx.x & 63;
    int wid  = threadIdx.x >> 6;
    if (lane == 0) wsum[wid] = acc;
    __syncthreads();
    if (threadIdx.x == 0) {
        float s = wsum[0] + wsum[1] + wsum[2] + wsum[3];
        partial[blockIdx.x] = s;
    }
}

__global__ __launch_bounds__(BLOCK) void ordloss_final(
    const f32x4* __restrict__ partial4,  // GRID/4 float4s
    float* __restrict__ out, float inv_count)
{
    // GRID=2048 partials = 512 float4; 256 threads x 2 float4 each.
    f32x4 a = partial4[threadIdx.x];
    f32x4 b = partial4[threadIdx.x + BLOCK];
    float acc = (a[0] + a[1]) + (a[2] + a[3]) + (b[0] + b[1]) + (b[2] + b[3]);

#pragma unroll
    for (int off = 32; off > 0; off >>= 1)
        acc += __shfl_down(acc, off, 64);

    __shared__ float wsum[BLOCK / 64];
    int lane = threadIdx.x & 63;
    int wid  = threadIdx.x >> 6;
    if (lane == 0) wsum[wid] = acc;
    __syncthreads();
    if (threadIdx.x == 0) {
        float s = wsum[0] + wsum[1] + wsum[2] + wsum[3];
        out[0] = s * inv_count;
    }
}

extern "C" void kernel_launch(void* const* d_in, const int* in_sizes, int n_in,
                              void* d_out, int out_size, void* d_ws, size_t ws_size,
                              hipStream_t stream) {
    const f32x4* logits = (const f32x4*)d_in[0];
    const int*   labels = (const int*)d_in[1];
    float*       out    = (float*)d_out;
    float*       partial = (float*)d_ws;   // GRID floats = 8 KiB

    int B = in_sizes[1];  // labels count = rows
    float inv_count = 1.0f / ((float)B * (float)KDIM);

    ordloss_partial<<<GRID, BLOCK, 0, stream>>>(logits, labels, partial, B);
    ordloss_final<<<1, BLOCK, 0, stream>>>((const f32x4*)partial, out, inv_count);
}